// Round 17
// baseline (63.125 us; speedup 1.0000x reference)
//
#include <hip/hip_runtime.h>
#include <hip/hip_bf16.h>
#include <math.h>

// BahdanauAttention on MI355X (gfx950).
// query (16,64,1024) f32, keys (16,128,1024) f32, Wq/Wk (1024,1024) f32,
// la (1024), scalar (1), bias (1024). Outputs: context (16,64,1024) then
// scores (16,64,128), concatenated flat f32.
//
// Round-17: 5 kernels -> 3 (dispatch overhead was ~half the runtime).
//  K1 gemm+prep: fp32->bf16 cast fused into GEMM staging (reg-staged, r12
//     structure); block 768 does la prep. aqE = exp2(ALPHA*q@Wq^T);
//     akE = exp2(ALPHA*(Wk@keys^T + bias)).
//  K2 scores: partials (pair-combined, lane=q / wave=k-slice; r16)
//  K3 softmax+ctx: per (b,nc) block: sum partials (redundant, L2-resident),
//     softmax in-LDS, nc==0 writes out_scores, then ctx = p @ keys.

#define ALPHA_2LOG2E 2.8853900817779268f
#define LOG2E 1.4426950408889634f

typedef __attribute__((ext_vector_type(8))) short short8;
typedef __attribute__((ext_vector_type(4))) float f32x4;
typedef __attribute__((ext_vector_type(2))) float f32x2;

static __device__ __forceinline__ short f2bf(float f) {
    union { float f; unsigned u; } v; v.f = f;
    unsigned r = v.u + 0x7fffu + ((v.u >> 16) & 1u);   // round-nearest-even
    return (short)(r >> 16);
}

static __device__ __forceinline__ short8 cvt8(float4 a, float4 b) {
    short8 o;
    o[0] = f2bf(a.x); o[1] = f2bf(a.y); o[2] = f2bf(a.z); o[3] = f2bf(a.w);
    o[4] = f2bf(b.x); o[5] = f2bf(b.y); o[6] = f2bf(b.z); o[7] = f2bf(b.w);
    return o;
}

// ---------------- K1: bf16 MFMA NT-GEMM with fused fp32->bf16 staging ----------------
// bid < 256 : aqE = exp2(ALPHA*(query @ Wq^T)),          ldc 1024
// bid < 768 : akE = exp2(ALPHA*(Wk @ keys^T + bias[m])), ldc 2048
// bid == 768: la prep (la2 = 2*la_n, Sla = sum la_n)
// 64x64 tile, BK=32, 256 thr (2x2 waves, 32x32 each), double-buffered LDS;
// staging: thread t loads 8 fp32 of A-row t>>2 (slot t&3), converts, ds_writes.
__global__ __launch_bounds__(256) void gemm_prep_kernel(
    const float* __restrict__ query, const float* __restrict__ keys,
    const float* __restrict__ wq, const float* __restrict__ wk,
    const float* __restrict__ bias,
    const float* __restrict__ la, const float* __restrict__ scal,
    float* __restrict__ aqE, float* __restrict__ akE,
    float* __restrict__ la2, float* __restrict__ sla)
{
    const int bid = blockIdx.x;
    if (bid == 768) {   // la prep
        __shared__ float red[4];
        const int t = threadIdx.x, lane = t & 63, w = t >> 6;
        float ss = 0.f;
        for (int i = t; i < 1024; i += 256) { float v = la[i]; ss = fmaf(v, v, ss); }
        #pragma unroll
        for (int off = 32; off; off >>= 1) ss += __shfl_xor(ss, off, 64);
        if (lane == 0) red[w] = ss;
        __syncthreads();
        const float tot = red[0] + red[1] + red[2] + red[3];
        const float sc = scal[0] / sqrtf(tot);
        float s2 = 0.f;
        for (int i = t; i < 1024; i += 256) {
            float v = la[i] * sc;
            la2[i] = 2.f * v;
            s2 += v;
        }
        #pragma unroll
        for (int off = 32; off; off >>= 1) s2 += __shfl_xor(s2, off, 64);
        __syncthreads();
        if (lane == 0) red[w] = s2;
        __syncthreads();
        if (t == 0) sla[0] = red[0] + red[1] + red[2] + red[3];
        return;
    }

    __shared__ short As[2][64][32];
    __shared__ short Bs[2][64][32];

    const float* A; const float* W; float* C; int useBias, bm, bn, ldc;
    if (bid < 256) {
        A = query; W = wq; C = aqE; useBias = 0; ldc = 1024;
        bm = (bid & 15) * 64; bn = (bid >> 4) * 64;
    } else {
        int b2 = bid - 256;
        A = wk; W = keys; C = akE; useBias = 1; ldc = 2048;
        bm = (b2 & 15) * 64; bn = (b2 >> 4) * 64;
    }

    const int t = threadIdx.x;
    const int lane = t & 63, wid = t >> 6;
    const int wr = wid >> 1, wc = wid & 1;      // 2x2 waves -> 32x32 tiles
    const int fr = lane & 15, fg = lane >> 4;

    const int sRow = t >> 2, sSlot = t & 3;
    const float* gA = A + (size_t)(bm + sRow) * 1024 + (sSlot << 3);
    const float* gW = W + (size_t)(bn + sRow) * 1024 + (sSlot << 3);

    const f32x4 zero = {0.f, 0.f, 0.f, 0.f};
    f32x4 acc[2][2];
    acc[0][0] = zero; acc[0][1] = zero; acc[1][0] = zero; acc[1][1] = zero;

    // prologue: tile0 -> buf0; issue tile1 loads
    float4 a0 = *(const float4*)gA,        a1 = *(const float4*)(gA + 4);
    float4 w0 = *(const float4*)gW,        w1 = *(const float4*)(gW + 4);
    *(short8*)&As[0][sRow][sSlot << 3] = cvt8(a0, a1);
    *(short8*)&Bs[0][sRow][sSlot << 3] = cvt8(w0, w1);
    a0 = *(const float4*)(gA + 32); a1 = *(const float4*)(gA + 36);
    w0 = *(const float4*)(gW + 32); w1 = *(const float4*)(gW + 36);
    asm volatile("s_waitcnt lgkmcnt(0)" ::: "memory");
    __builtin_amdgcn_s_barrier();
    asm volatile("" ::: "memory");

    #pragma unroll 1
    for (int kt = 0; kt < 32; ++kt) {
        const int cur = kt & 1;
        short8 af[2], bfr[2];
        #pragma unroll
        for (int mi = 0; mi < 2; ++mi)
            af[mi] = *(const short8*)&As[cur][wr * 32 + mi * 16 + fr][fg * 8];
        #pragma unroll
        for (int ni = 0; ni < 2; ++ni)
            bfr[ni] = *(const short8*)&Bs[cur][wc * 32 + ni * 16 + fr][fg * 8];
        if (kt < 31) {   // write tile kt+1 (regs loaded last iter)
            *(short8*)&As[cur ^ 1][sRow][sSlot << 3] = cvt8(a0, a1);
            *(short8*)&Bs[cur ^ 1][sRow][sSlot << 3] = cvt8(w0, w1);
        }
        if (kt < 30) {   // issue tile kt+2 loads (in flight under MFMAs)
            const int ko = (kt + 2) << 5;
            a0 = *(const float4*)(gA + ko);      a1 = *(const float4*)(gA + ko + 4);
            w0 = *(const float4*)(gW + ko);      w1 = *(const float4*)(gW + ko + 4);
        }
        #pragma unroll
        for (int mi = 0; mi < 2; ++mi)
            #pragma unroll
            for (int ni = 0; ni < 2; ++ni)
                acc[mi][ni] = __builtin_amdgcn_mfma_f32_16x16x32_bf16(
                    af[mi], bfr[ni], acc[mi][ni], 0, 0, 0);
        asm volatile("s_waitcnt lgkmcnt(0)" ::: "memory");
        __builtin_amdgcn_s_barrier();
        asm volatile("" ::: "memory");
    }

    // C/D: col=lane&15, row=(lane>>4)*4+reg; epilogue: exp2(ALPHA*(v+bias))
    float* Cb = C + (size_t)bm * ldc;
    #pragma unroll
    for (int mi = 0; mi < 2; ++mi) {
        const int row0 = wr * 32 + mi * 16 + fg * 4;
        float brow[4] = {0.f, 0.f, 0.f, 0.f};
        if (useBias) {
            #pragma unroll
            for (int r = 0; r < 4; ++r) brow[r] = bias[bm + row0 + r];
        }
        #pragma unroll
        for (int ni = 0; ni < 2; ++ni) {
            const int col = bn + wc * 32 + ni * 16 + fr;
            #pragma unroll
            for (int r = 0; r < 4; ++r)
                Cb[(size_t)(row0 + r) * ldc + col] =
                    __builtin_amdgcn_exp2f((acc[mi][ni][r] + brow[r]) * ALPHA_2LOG2E);
        }
    }
}

// ---------------- K2: scores partials, lane=q / wave=k-slice (r16) ----------------
// grid (16 b, 16 nc), 1024 thr (16 waves). Wave w -> k in [8w, 8w+8);
// lane -> q. Pair-combined over n: 1 rcp / 2 elements.
__global__ __launch_bounds__(1024) void scores_part_kernel(
    const float* __restrict__ aqE, const float* __restrict__ akE,
    const float* __restrict__ la2, float* __restrict__ partials)
{
    const int b = blockIdx.x, nc = blockIdx.y;
    const int t = threadIdx.x, w = t >> 6, lane = t & 63;

    __shared__ f32x2 eqP[32][64];    // [n-pair][q] 16 KB
    __shared__ float eks[64][128];   // [n][k]      32 KB
    __shared__ float l2s[64];

    {
        const int qq = t >> 4, nj = (t & 15) << 2;
        float4 v = *(const float4*)(aqE + ((size_t)((b << 6) + qq) << 10) + (nc << 6) + nj);
        f32x2 p0 = {v.x, v.y}, p1 = {v.z, v.w};
        eqP[nj >> 1][qq] = p0;
        eqP[(nj >> 1) + 1][qq] = p1;
        const int n = t >> 4, k0 = (t & 15) << 3;
        const float* src = akE + ((size_t)((nc << 6) + n) << 11) + (b << 7) + k0;
        *(float4*)&eks[n][k0]     = *(const float4*)src;
        *(float4*)&eks[n][k0 + 4] = *(const float4*)(src + 4);
        if (t < 64) l2s[t] = la2[(nc << 6) + t];
    }
    __syncthreads();

    const int k0 = w << 3;
    f32x2 acc[4];
    #pragma unroll
    for (int j = 0; j < 4; ++j) acc[j] = (f32x2){0.f, 0.f};

    #pragma unroll 4
    for (int np = 0; np < 32; ++np) {
        const int n0 = np << 1;
        const f32x4 e0a = *(const f32x4*)&eks[n0][k0];
        const f32x4 e0b = *(const f32x4*)&eks[n0][k0 + 4];
        const f32x4 e1a = *(const f32x4*)&eks[n0 + 1][k0];
        const f32x4 e1b = *(const f32x4*)&eks[n0 + 1][k0 + 4];
        const f32x2 l2 = *(const f32x2*)&l2s[n0];
        const float S = l2.x + l2.y;
        const f32x2 eq = eqP[np][lane];
        const f32x2 Svec = {S, S};

        f32x2 ek0[4], ek1[4];
        ek0[0] = (f32x2){e0a.x, e0a.y}; ek0[1] = (f32x2){e0a.z, e0a.w};
        ek0[2] = (f32x2){e0b.x, e0b.y}; ek0[3] = (f32x2){e0b.z, e0b.w};
        ek1[0] = (f32x2){e1a.x, e1a.y}; ek1[1] = (f32x2){e1a.z, e1a.w};
        ek1[2] = (f32x2){e1b.x, e1b.y}; ek1[3] = (f32x2){e1b.z, e1b.w};

        #pragma unroll
        for (int j = 0; j < 4; ++j) {
            const f32x2 E0 = eq.x * ek0[j];
            const f32x2 E1 = eq.y * ek1[j];
            const f32x2 d1 = E1 + 1.f;
            const f32x2 D  = E0 * d1 + d1;       // (1+E0)(1+E1)
            const f32x2 num = l2.x * E1 + (l2.y * E0 + Svec);
            f32x2 r;
            r.x = __builtin_amdgcn_rcpf(D.x);
            r.y = __builtin_amdgcn_rcpf(D.y);
            acc[j] = num * r + acc[j];
        }
    }

    float* pp = partials + ((size_t)((b << 4) + nc) << 13) + (lane << 7) + k0;
    #pragma unroll
    for (int j = 0; j < 4; ++j)
        *(f32x2*)(pp + (j << 1)) = acc[j];
}

// ---------------- K3: reduce + softmax + context (B merged into C) ----------------
// grid (16 b, 16 nc), 512 thr (8 waves). Each block: sum its batch's 16
// partial-chunks into ps[64][128] (redundant per nc-block; L2-resident),
// softmax per q-row (wave w -> rows 8w..8w+7), nc==0 writes out_scores,
// then ctx = p @ keys for its 64-col slice.
__global__ __launch_bounds__(512) void softmax_ctx_kernel(
    const float* __restrict__ partials, const float* __restrict__ sla,
    const float* __restrict__ keys,
    float* __restrict__ ctx, float* __restrict__ out_scores)
{
    const int b = blockIdx.x, nc = blockIdx.y;
    const int t = threadIdx.x, w = t >> 6, lane = t & 63;

    __shared__ float ps[64][128];   // raw sums -> probs, 32 KB
    __shared__ float ks[128][64];   // [k][n] 32 KB

    // stage keys slice
    {
        const int k = t >> 2, n0 = (t & 3) << 4;
        const float* src = keys + ((size_t)((b << 7) + k) << 10) + (nc << 6) + n0;
        #pragma unroll
        for (int i = 0; i < 4; ++i)
            *(float4*)&ks[k][n0 + (i << 2)] = *(const float4*)(src + (i << 2));
    }
    // sum partials: 4096 k-pair elems, 8 per thread
    #pragma unroll
    for (int i = 0; i < 8; ++i) {
        const int e = (i << 9) + t;
        const int q = e >> 6, kp = e & 63;
        const float* pq = partials + ((size_t)b << 17) + (q << 7) + (kp << 1);
        f32x2 s = {0.f, 0.f};
        #pragma unroll
        for (int c = 0; c < 16; ++c)
            s += *(const f32x2*)(pq + ((size_t)c << 13));
        *(f32x2*)&ps[q][kp << 1] = s;
    }
    __syncthreads();

    // softmax: wave w -> q rows 8w..8w+7 (lane holds k=2l,2l+1)
    const float Sla = sla[0];
    #pragma unroll
    for (int r = 0; r < 8; ++r) {
        const int q = (w << 3) + r;
        const float2 v = *(const float2*)&ps[q][lane << 1];
        float s0 = Sla - v.x, s1 = Sla - v.y;
        float m = fmaxf(s0, s1);
        #pragma unroll
        for (int off = 32; off; off >>= 1) m = fmaxf(m, __shfl_xor(m, off, 64));
        float e0 = __builtin_amdgcn_exp2f((s0 - m) * LOG2E);
        float e1 = __builtin_amdgcn_exp2f((s1 - m) * LOG2E);
        float s = e0 + e1;
        #pragma unroll
        for (int off = 32; off; off >>= 1) s += __shfl_xor(s, off, 64);
        const float inv = __builtin_amdgcn_rcpf(s);
        float2 p = {e0 * inv, e1 * inv};
        *(float2*)&ps[q][lane << 1] = p;
        if (nc == 0)
            *(float2*)(out_scores + ((size_t)((b << 6) + q) << 7) + (lane << 1)) = p;
    }
    __syncthreads();

    // context: thread -> 4 q x 2 n over 128 k
    const int q0 = (t >> 5) << 2;
    const int n0 = (t & 31) << 1;
    float acc[4][2];
    #pragma unroll
    for (int i = 0; i < 4; ++i) { acc[i][0] = 0.f; acc[i][1] = 0.f; }

    #pragma unroll 8
    for (int k = 0; k < 128; ++k) {
        const float2 kv = *(const float2*)&ks[k][n0];
        #pragma unroll
        for (int i = 0; i < 4; ++i) {
            const float p = ps[q0 + i][k];
            acc[i][0] = fmaf(p, kv.x, acc[i][0]);
            acc[i][1] = fmaf(p, kv.y, acc[i][1]);
        }
    }
    #pragma unroll
    for (int i = 0; i < 4; ++i) {
        float2 v = {acc[i][0], acc[i][1]};
        *(float2*)(ctx + ((size_t)((b << 6) + q0 + i) << 10) + (nc << 6) + n0) = v;
    }
}

extern "C" void kernel_launch(void* const* d_in, const int* in_sizes, int n_in,
                              void* d_out, int out_size, void* d_ws, size_t ws_size,
                              hipStream_t stream) {
    const float* query  = (const float*)d_in[0];
    const float* keys   = (const float*)d_in[1];
    const float* Wq     = (const float*)d_in[2];
    const float* Wk     = (const float*)d_in[3];
    const float* la     = (const float*)d_in[4];
    const float* scal   = (const float*)d_in[5];
    const float* bias   = (const float*)d_in[6];

    float* ws  = (float*)d_ws;
    float* aqE = ws;                        // 1M f32 (4 MB), [1024 q][1024 n]
    float* akE = ws + (1u << 20);           // 2M f32 (8 MB), [1024 n][2048 bk]
    float* la2 = akE + (2u << 20);          // 1024 f32
    float* sla = la2 + 1024;                // 1 f32
    float* partials = sla + 1024;           // 2M f32 (8 MB): [16b][16nc][64q][128k]

    float* ctx        = (float*)d_out;
    float* out_scores = ctx + (size_t)16 * 64 * 1024;

    gemm_prep_kernel<<<769, 256, 0, stream>>>(query, keys, Wq, Wk, bias, la, scal,
                                              aqE, akE, la2, sla);
    scores_part_kernel<<<dim3(16, 16), 1024, 0, stream>>>(aqE, akE, la2, partials);
    softmax_ctx_kernel<<<dim3(16, 16), 512, 0, stream>>>(partials, sla, keys,
                                                         ctx, out_scores);
}

// Round 18
// 60.103 us; speedup vs baseline: 1.0503x; 1.0503x over previous
//
#include <hip/hip_runtime.h>
#include <hip/hip_bf16.h>
#include <math.h>

// BahdanauAttention on MI355X (gfx950).
// query (16,64,1024) f32, keys (16,128,1024) f32, Wq/Wk (1024,1024) f32,
// la (1024), scalar (1), bias (1024). Outputs: context (16,64,1024) then
// scores (16,64,128), concatenated flat f32.
//
// Round-18: r14 base (best, 59.6us) + QUAD-combine in A: 4 n-terms share one
// rcp via common denominator (P01*P23). rcp count per 8 evals: 4 -> 2.
//  K0 cast+prep: q/k/Wq/Wk -> bf16; la2/Sla
//  K1 gemm (64x64, gload_lds dbuf): aqE = exp2(ALPHA*q@Wq^T); akE = exp2(...)
//  A: partials (quad-combined, 1 rcp / 4 elems)
//  B: reduce + softmax -> p_buf + out_scores
//  C: ctx = p @ keys (LDS-staged)

#define ALPHA_2LOG2E 2.8853900817779268f
#define LOG2E 1.4426950408889634f

typedef __attribute__((ext_vector_type(8))) short short8;
typedef __attribute__((ext_vector_type(4))) float f32x4;
typedef __attribute__((ext_vector_type(2))) float f32x2;

static __device__ __forceinline__ short f2bf(float f) {
    union { float f; unsigned u; } v; v.f = f;
    unsigned r = v.u + 0x7fffu + ((v.u >> 16) & 1u);   // round-nearest-even
    return (short)(r >> 16);
}

// async global->LDS, 16B per lane; lds base wave-uniform (HW adds lane*16)
static __device__ __forceinline__ void gload16(const void* g, void* l) {
    __builtin_amdgcn_global_load_lds(
        (const __attribute__((address_space(1))) unsigned*)g,
        (__attribute__((address_space(3))) unsigned*)l, 16, 0, 0);
}

// ---------------- K0: fp32 -> bf16 cast, plus la prep in last block ----------------
__global__ __launch_bounds__(256) void cast_prep_kernel(
    const float* __restrict__ q, const float* __restrict__ k,
    const float* __restrict__ wq, const float* __restrict__ wk,
    short* __restrict__ qb, short* __restrict__ kb,
    short* __restrict__ wqb, short* __restrict__ wkb,
    const float* __restrict__ la, const float* __restrict__ scal,
    float* __restrict__ la2, float* __restrict__ sla)
{
    const int bid = blockIdx.x;
    if (bid == 2560) {   // la prep
        __shared__ float red[4];
        const int t = threadIdx.x, lane = t & 63, w = t >> 6;
        float ss = 0.f;
        for (int i = t; i < 1024; i += 256) { float v = la[i]; ss = fmaf(v, v, ss); }
        #pragma unroll
        for (int off = 32; off; off >>= 1) ss += __shfl_xor(ss, off, 64);
        if (lane == 0) red[w] = ss;
        __syncthreads();
        const float tot = red[0] + red[1] + red[2] + red[3];
        const float sc = scal[0] / sqrtf(tot);
        float s2 = 0.f;
        for (int i = t; i < 1024; i += 256) {
            float v = la[i] * sc;
            la2[i] = 2.f * v;
            s2 += v;
        }
        #pragma unroll
        for (int off = 32; off; off >>= 1) s2 += __shfl_xor(s2, off, 64);
        __syncthreads();
        if (lane == 0) red[w] = s2;
        __syncthreads();
        if (t == 0) sla[0] = red[0] + red[1] + red[2] + red[3];
        return;
    }
    const float* src; short* dst; int base;
    if (bid < 512)       { src = q;  dst = qb;  base = bid; }
    else if (bid < 1536) { src = k;  dst = kb;  base = bid - 512; }
    else if (bid < 2048) { src = wq; dst = wqb; base = bid - 1536; }
    else                 { src = wk; dst = wkb; base = bid - 2048; }
    const size_t i = ((size_t)base * 256 + threadIdx.x) * 8;
    float4 a = *reinterpret_cast<const float4*>(src + i);
    float4 b = *reinterpret_cast<const float4*>(src + i + 4);
    short8 o;
    o[0] = f2bf(a.x); o[1] = f2bf(a.y); o[2] = f2bf(a.z); o[3] = f2bf(a.w);
    o[4] = f2bf(b.x); o[5] = f2bf(b.y); o[6] = f2bf(b.z); o[7] = f2bf(b.w);
    *reinterpret_cast<short8*>(dst + i) = o;
}

// ---------------- K1: bf16 MFMA NT-GEMM, 64x64 tile, gload_lds dbuf (r14) ----------------
__global__ __launch_bounds__(256) void gemm_mfma_kernel(
    const short* __restrict__ qb, const short* __restrict__ kb,
    const short* __restrict__ wqb, const short* __restrict__ wkb,
    const float* __restrict__ bias,
    float* __restrict__ aqE, float* __restrict__ akE)
{
    __shared__ short As[2][64][32];
    __shared__ short Bs[2][64][32];

    const int bid = blockIdx.x;
    const short* A; const short* W; float* C; int useBias, bm, bn, ldc;
    if (bid < 256) {
        A = qb;  W = wqb; C = aqE; useBias = 0; ldc = 1024;
        bm = (bid & 15) * 64; bn = (bid >> 4) * 64;
    } else {
        int b2 = bid - 256;
        A = wkb; W = kb;  C = akE; useBias = 1; ldc = 2048;
        bm = (b2 & 15) * 64; bn = (b2 >> 4) * 64;
    }

    const int t = threadIdx.x;
    const int lane = t & 63, wid = t >> 6;
    const int wr = wid >> 1, wc = wid & 1;      // 2x2 waves -> 32x32 tiles
    const int fr = lane & 15, fg = lane >> 4;

    const short* gA0 = A + (size_t)(bm + (wid << 4) + (lane >> 2)) * 1024 + ((lane & 3) << 3);
    const short* gB0 = W + (size_t)(bn + (wid << 4) + (lane >> 2)) * 1024 + ((lane & 3) << 3);

    const f32x4 zero = {0.f, 0.f, 0.f, 0.f};
    f32x4 acc[2][2];
    acc[0][0] = zero; acc[0][1] = zero; acc[1][0] = zero; acc[1][1] = zero;

    gload16(gA0, &As[0][wid << 4][0]);
    gload16(gB0, &Bs[0][wid << 4][0]);
    asm volatile("s_waitcnt vmcnt(0)" ::: "memory");
    __builtin_amdgcn_s_barrier();
    asm volatile("" ::: "memory");

    #pragma unroll 1
    for (int kt = 0; kt < 32; ++kt) {
        const int cur = kt & 1;
        if (kt < 31) {
            const int ko = (kt + 1) << 5;
            gload16(gA0 + ko, &As[cur ^ 1][wid << 4][0]);
            gload16(gB0 + ko, &Bs[cur ^ 1][wid << 4][0]);
        }
        short8 af[2], bfr[2];
        #pragma unroll
        for (int mi = 0; mi < 2; ++mi)
            af[mi] = *(const short8*)&As[cur][wr * 32 + mi * 16 + fr][fg * 8];
        #pragma unroll
        for (int ni = 0; ni < 2; ++ni)
            bfr[ni] = *(const short8*)&Bs[cur][wc * 32 + ni * 16 + fr][fg * 8];
        #pragma unroll
        for (int mi = 0; mi < 2; ++mi)
            #pragma unroll
            for (int ni = 0; ni < 2; ++ni)
                acc[mi][ni] = __builtin_amdgcn_mfma_f32_16x16x32_bf16(
                    af[mi], bfr[ni], acc[mi][ni], 0, 0, 0);
        asm volatile("s_waitcnt vmcnt(0) lgkmcnt(0)" ::: "memory");
        __builtin_amdgcn_s_barrier();
        asm volatile("" ::: "memory");
    }

    // C/D: col=lane&15, row=(lane>>4)*4+reg; epilogue: exp2(ALPHA*(v+bias))
    float* Cb = C + (size_t)bm * ldc;
    #pragma unroll
    for (int mi = 0; mi < 2; ++mi) {
        const int row0 = wr * 32 + mi * 16 + fg * 4;
        float brow[4] = {0.f, 0.f, 0.f, 0.f};
        if (useBias) {
            #pragma unroll
            for (int r = 0; r < 4; ++r) brow[r] = bias[bm + row0 + r];
        }
        #pragma unroll
        for (int ni = 0; ni < 2; ++ni) {
            const int col = bn + wc * 32 + ni * 16 + fr;
            #pragma unroll
            for (int r = 0; r < 4; ++r)
                Cb[(size_t)(row0 + r) * ldc + col] =
                    __builtin_amdgcn_exp2f((acc[mi][ni][r] + brow[r]) * ALPHA_2LOG2E);
        }
    }
}

// ---------------- A: scores partials, QUAD-combined over n ----------------
// grid (16 b, 16 nc), 1024 thr (16 waves). Wave w -> q rows [4w,4w+4);
// lane -> k-pair {2l, 2l+1} packed f32x2. Per n-quad (n0..n0+3):
//   P01=(1+E0)(1+E1), P23=(1+E2)(1+E3)
//   sum = (numA*P23 + numB*P01) * rcp(P01*P23)   [1 rcp / 4 elems]
// where numA = la0+la1+la0*E1+la1*E0 (the pair numerator), numB likewise.
__global__ __launch_bounds__(1024) void scores_part_kernel(
    const float* __restrict__ aqE, const float* __restrict__ akE,
    const float* __restrict__ la2, float* __restrict__ partials)
{
    const int b = blockIdx.x, nc = blockIdx.y;
    const int t = threadIdx.x, w = t >> 6, lane = t & 63;

    __shared__ float eqs[64][64];    // [q][n]  16 KB
    __shared__ float eks[64][128];   // [n][k]  32 KB
    __shared__ float l2s[64];

    {
        const int qq = t >> 4, nj = (t & 15) << 2;
        *(float4*)&eqs[qq][nj] =
            *(const float4*)(aqE + ((size_t)((b << 6) + qq) << 10) + (nc << 6) + nj);
        const int n = t >> 4, k0 = (t & 15) << 3;
        const float* src = akE + ((size_t)((nc << 6) + n) << 11) + (b << 7) + k0;
        *(float4*)&eks[n][k0]     = *(const float4*)src;
        *(float4*)&eks[n][k0 + 4] = *(const float4*)(src + 4);
        if (t < 64) l2s[t] = la2[(nc << 6) + t];
    }
    __syncthreads();

    const int q0 = w << 2;
    f32x2 acc[4];
    #pragma unroll
    for (int i = 0; i < 4; ++i) acc[i] = (f32x2){0.f, 0.f};

    const int kb2 = lane << 1;
    #pragma unroll 2
    for (int nq = 0; nq < 16; ++nq) {
        const int n0 = nq << 2;
        const f32x2 ek0 = *(const f32x2*)&eks[n0][kb2];
        const f32x2 ek1 = *(const f32x2*)&eks[n0 + 1][kb2];
        const f32x2 ek2 = *(const f32x2*)&eks[n0 + 2][kb2];
        const f32x2 ek3 = *(const f32x2*)&eks[n0 + 3][kb2];
        const f32x4 l4 = *(const f32x4*)&l2s[n0];       // la0..la3 (broadcast)
        const float SA = l4.x + l4.y;
        const float SB = l4.z + l4.w;
        #pragma unroll
        for (int i = 0; i < 4; ++i) {
            const f32x4 eq = *(const f32x4*)&eqs[q0 + i][n0];   // broadcast
            const f32x2 E0 = eq.x * ek0;
            const f32x2 E1 = eq.y * ek1;
            const f32x2 E2 = eq.z * ek2;
            const f32x2 E3 = eq.w * ek3;
            const f32x2 d1 = E1 + 1.f;
            const f32x2 d3 = E3 + 1.f;
            const f32x2 P01 = E0 * d1 + d1;             // (1+E0)(1+E1)
            const f32x2 P23 = E2 * d3 + d3;             // (1+E2)(1+E3)
            const f32x2 numA = l4.x * E1 + (l4.y * E0 + SA);
            const f32x2 numB = l4.z * E3 + (l4.w * E2 + SB);
            const f32x2 num = numA * P23 + numB * P01;
            const f32x2 D = P01 * P23;
            f32x2 r;
            r.x = __builtin_amdgcn_rcpf(D.x);
            r.y = __builtin_amdgcn_rcpf(D.y);
            acc[i] = num * r + acc[i];
        }
    }

    float* pp = partials + ((size_t)((b << 4) + nc) << 13) + kb2;
    #pragma unroll
    for (int i = 0; i < 4; ++i)
        *(f32x2*)(pp + ((q0 + i) << 7)) = acc[i];
}

// ---------------- B: reduce partials + softmax ----------------
__global__ __launch_bounds__(256) void reduce_softmax_kernel(
    const float* __restrict__ partials, const float* __restrict__ sla,
    float* __restrict__ p_buf, float* __restrict__ out_scores)
{
    const int b = blockIdx.x, qo = blockIdx.y;
    const int t = threadIdx.x, w = t >> 6, lane = t & 63;
    const int q = (qo << 2) + w;

    const float* pp = partials + ((size_t)b << 17) + (q << 7) + (lane << 1);
    float s0 = 0.f, s1 = 0.f;
    #pragma unroll
    for (int nc = 0; nc < 16; ++nc) {
        const float2 v = *(const float2*)(pp + ((size_t)nc << 13));
        s0 += v.x; s1 += v.y;
    }
    const float Sla = sla[0];
    s0 = Sla - s0; s1 = Sla - s1;
    float m = fmaxf(s0, s1);
    #pragma unroll
    for (int off = 32; off; off >>= 1) m = fmaxf(m, __shfl_xor(m, off, 64));
    float e0 = __builtin_amdgcn_exp2f((s0 - m) * LOG2E);
    float e1 = __builtin_amdgcn_exp2f((s1 - m) * LOG2E);
    float s = e0 + e1;
    #pragma unroll
    for (int off = 32; off; off >>= 1) s += __shfl_xor(s, off, 64);
    const float inv = __builtin_amdgcn_rcpf(s);
    float2 p = {e0 * inv, e1 * inv};
    *(float2*)(p_buf + ((size_t)((b << 6) + q) << 7) + (lane << 1)) = p;
    *(float2*)(out_scores + ((size_t)((b << 6) + q) << 7) + (lane << 1)) = p;
}

// ---------------- C: context = p @ keys (LDS-staged, keys read once) ----------------
__global__ __launch_bounds__(512) void ctx_kernel(
    const float* __restrict__ p_buf, const float* __restrict__ keys,
    float* __restrict__ ctx)
{
    const int b = blockIdx.x, nc = blockIdx.y;
    const int t = threadIdx.x;

    __shared__ float ks[128][64];   // [k][n] 32 KB
    __shared__ float ps[64][128];   // [q][k] 32 KB

    {
        const int k = t >> 2, n0 = (t & 3) << 4;
        const float* src = keys + ((size_t)((b << 7) + k) << 10) + (nc << 6) + n0;
        #pragma unroll
        for (int i = 0; i < 4; ++i)
            *(float4*)&ks[k][n0 + (i << 2)] = *(const float4*)(src + (i << 2));
        const int qq = t >> 3, k0 = (t & 7) << 4;
        const float* psrc = p_buf + ((size_t)((b << 6) + qq) << 7) + k0;
        #pragma unroll
        for (int i = 0; i < 4; ++i)
            *(float4*)&ps[qq][k0 + (i << 2)] = *(const float4*)(psrc + (i << 2));
    }
    __syncthreads();

    const int q0 = (t >> 5) << 2;
    const int n0 = (t & 31) << 1;
    float acc[4][2];
    #pragma unroll
    for (int i = 0; i < 4; ++i) { acc[i][0] = 0.f; acc[i][1] = 0.f; }

    #pragma unroll 8
    for (int k = 0; k < 128; ++k) {
        const float2 kv = *(const float2*)&ks[k][n0];
        #pragma unroll
        for (int i = 0; i < 4; ++i) {
            const float p = ps[q0 + i][k];
            acc[i][0] = fmaf(p, kv.x, acc[i][0]);
            acc[i][1] = fmaf(p, kv.y, acc[i][1]);
        }
    }
    #pragma unroll
    for (int i = 0; i < 4; ++i) {
        float2 v = {acc[i][0], acc[i][1]};
        *(float2*)(ctx + ((size_t)((b << 6) + q0 + i) << 10) + (nc << 6) + n0) = v;
    }
}

extern "C" void kernel_launch(void* const* d_in, const int* in_sizes, int n_in,
                              void* d_out, int out_size, void* d_ws, size_t ws_size,
                              hipStream_t stream) {
    const float* query  = (const float*)d_in[0];
    const float* keys   = (const float*)d_in[1];
    const float* Wq     = (const float*)d_in[2];
    const float* Wk     = (const float*)d_in[3];
    const float* la     = (const float*)d_in[4];
    const float* scal   = (const float*)d_in[5];
    const float* bias   = (const float*)d_in[6];

    float* ws  = (float*)d_ws;
    float* aqE = ws;                        // 1M f32 (4 MB)
    float* akE = ws + (1u << 20);           // 2M f32 (8 MB)
    float* la2 = akE + (2u << 20);          // 1024 f32
    float* sla = la2 + 1024;                // 1 f32
    short* qb  = (short*)(ws + 3 * 1048576 + 2048);  // 1M bf16 (2 MB)
    short* kb  = qb + 1048576;                       // 2M bf16 (4 MB)
    short* wqb = kb + 2097152;                       // 1M bf16 (2 MB)
    short* wkb = wqb + 1048576;                      // 1M bf16 (2 MB)
    float* partials = (float*)kb;           // aliases kb..wkb (dead after gemm), 8 MB
    float* p_buf    = (float*)qb;           // aliases qb, 512 KB

    float* ctx        = (float*)d_out;
    float* out_scores = ctx + (size_t)16 * 64 * 1024;

    cast_prep_kernel<<<2561, 256, 0, stream>>>(query, keys, Wq, Wk, qb, kb, wqb, wkb,
                                               la, scal, la2, sla);
    gemm_mfma_kernel<<<768, 256, 0, stream>>>(qb, kb, wqb, wkb, bias, aqE, akE);
    scores_part_kernel<<<dim3(16, 16), 1024, 0, stream>>>(aqE, akE, la2, partials);
    reduce_softmax_kernel<<<dim3(16, 16), 256, 0, stream>>>(partials, sla, p_buf, out_scores);
    ctx_kernel<<<dim3(16, 16), 512, 0, stream>>>(p_buf, keys, ctx);
}